// Round 2
// baseline (758.194 us; speedup 1.0000x reference)
//
#include <hip/hip_runtime.h>

#define N_NODES 100000
#define N_EDGES 3200000
#define NB ((N_NODES + 255) / 256)   // 391 blocks over nodes

// ---------------- CSR build ----------------

__global__ void k_deg(const int* __restrict__ dst, int* __restrict__ deg) {
  int e = blockIdx.x * blockDim.x + threadIdx.x;
  if (e < N_EDGES) atomicAdd(&deg[dst[e]], 1);
}

// Per-block exclusive scan of deg -> rs (local), block totals -> blksums.
// Also dis[n] = rsqrt(deg_with_self_loop) = rsqrt(deg[n]+1).
__global__ void k_scan1(const int* __restrict__ deg, int* __restrict__ rs,
                        float* __restrict__ dis, int* __restrict__ blksums) {
  __shared__ int sh[256];
  int tid = threadIdx.x;
  int i = blockIdx.x * 256 + tid;
  int v = (i < N_NODES) ? deg[i] : 0;
  if (i < N_NODES) dis[i] = rsqrtf((float)(v + 1));
  int x = v;
  sh[tid] = x;
  __syncthreads();
  for (int off = 1; off < 256; off <<= 1) {
    int t = (tid >= off) ? sh[tid - off] : 0;
    __syncthreads();
    x += t;
    sh[tid] = x;
    __syncthreads();
  }
  if (i < N_NODES) rs[i] = x - v;            // exclusive within block
  if (tid == 255) blksums[blockIdx.x] = x;   // block total
}

// Single-block exclusive scan of the 391 block sums (in place).
__global__ void k_scan2(int* blksums) {
  __shared__ int sh[512];
  int tid = threadIdx.x;
  int v = (tid < NB) ? blksums[tid] : 0;
  int x = v;
  sh[tid] = x;
  __syncthreads();
  for (int off = 1; off < 512; off <<= 1) {
    int t = (tid >= off) ? sh[tid - off] : 0;
    __syncthreads();
    x += t;
    sh[tid] = x;
    __syncthreads();
  }
  if (tid < NB) blksums[tid] = x - v;
}

__global__ void k_scan3(int* __restrict__ rs, int* __restrict__ cursor,
                        const int* __restrict__ blksums) {
  int i = blockIdx.x * 256 + threadIdx.x;
  if (i < N_NODES) {
    int r = rs[i] + blksums[blockIdx.x];
    rs[i] = r;
    cursor[i] = r;
  }
  if (i == 0) rs[N_NODES] = N_EDGES;
}

__global__ void k_fill(const int* __restrict__ src, const int* __restrict__ dst,
                       int* __restrict__ cursor, int* __restrict__ csr) {
  int e = blockIdx.x * blockDim.x + threadIdx.x;
  if (e < N_EDGES) {
    int d = dst[e];
    int pos = atomicAdd(&cursor[d], 1);
    csr[pos] = src[e];
  }
}

// ---------------- Layer 1: aggregate x (4 feats) then transform ----------------
// agg1[n] = dis[n] * ( x[n]*dis[n] + sum_{s in in(n)} x[s]*dis[s] )

__global__ void k_agg1(const float4* __restrict__ x4, const float* __restrict__ dis,
                       const int* __restrict__ rs, const int* __restrict__ csr,
                       float4* __restrict__ agg1) {
  int n = blockIdx.x * blockDim.x + threadIdx.x;
  if (n >= N_NODES) return;
  float dn = dis[n];
  float4 xv = x4[n];
  float ax = xv.x * dn, ay = xv.y * dn, az = xv.z * dn, aw = xv.w * dn;
  int e1 = rs[n + 1];
  for (int e = rs[n]; e < e1; ++e) {
    int s = csr[e];
    float ds_ = dis[s];
    float4 xs = x4[s];
    ax += xs.x * ds_; ay += xs.y * ds_; az += xs.z * ds_; aw += xs.w * ds_;
  }
  float4 r; r.x = ax * dn; r.y = ay * dn; r.z = az * dn; r.w = aw * dn;
  agg1[n] = r;
}

// h1[n][j] = relu(b1[j] + sum_k agg1[n][k] * W1[k][j])
__global__ void k_xform1(const float4* __restrict__ agg1, const float* __restrict__ W1,
                         const float* __restrict__ b1, float* __restrict__ h1) {
  int t = blockIdx.x * blockDim.x + threadIdx.x;
  if (t >= N_NODES * 64) return;
  int n = t >> 6, j = t & 63;
  float4 a = agg1[n];
  float s = b1[j] + a.x * W1[j] + a.y * W1[64 + j] + a.z * W1[128 + j] + a.w * W1[192 + j];
  h1[t] = fmaxf(s, 0.0f);
}

// ---------------- Layer 2 fused: aggregate h1, W2+b2+relu, Wf+bf head ----------------
// One wave per node; lane = feature. Block 256 = 4 nodes.
__global__ void __launch_bounds__(256)
k_layer2(const float* __restrict__ h1, const float* __restrict__ dis,
         const int* __restrict__ rs, const int* __restrict__ csr,
         const float* __restrict__ W2, const float* __restrict__ b2,
         const float* __restrict__ Wf, const float* __restrict__ bf,
         float* __restrict__ out) {
  __shared__ float sh[4][64];
  int lane = threadIdx.x & 63;
  int w = threadIdx.x >> 6;
  int n = blockIdx.x * 4 + w;   // grid = N/4 exactly, n always valid

  float dn = dis[n];
  float acc = h1[n * 64 + lane] * dn;   // self-loop term
  int e = rs[n], e1 = rs[n + 1];
  // manual unroll-2 for memory-level parallelism
  for (; e + 1 < e1; e += 2) {
    int s0 = csr[e], s1 = csr[e + 1];
    float d0 = dis[s0], d1 = dis[s1];
    float v0 = h1[s0 * 64 + lane];
    float v1 = h1[s1 * 64 + lane];
    acc += v0 * d0;
    acc += v1 * d1;
  }
  if (e < e1) {
    int s = csr[e];
    acc += h1[s * 64 + lane] * dis[s];
  }
  acc *= dn;                      // agg2[n][lane]

  sh[w][lane] = acc;
  __syncthreads();

  // h2[lane] = relu(b2[lane] + sum_j agg2[n][j] * W2[j][lane])
  float t = b2[lane];
#pragma unroll 16
  for (int j = 0; j < 64; ++j) t += sh[w][j] * W2[j * 64 + lane];
  t = fmaxf(t, 0.0f);

  // head: out[n][c] = sum_j h2[j] * Wf[j][c] + bf[c]
  float p0 = t * Wf[lane * 2 + 0];
  float p1 = t * Wf[lane * 2 + 1];
  for (int off = 32; off; off >>= 1) {
    p0 += __shfl_down(p0, off);
    p1 += __shfl_down(p1, off);
  }
  if (lane == 0) {
    out[n * 2 + 0] = p0 + bf[0];
    out[n * 2 + 1] = p1 + bf[1];
  }
}

// ---------------- launch ----------------

extern "C" void kernel_launch(void* const* d_in, const int* in_sizes, int n_in,
                              void* d_out, int out_size, void* d_ws, size_t ws_size,
                              hipStream_t stream) {
  const float* x  = (const float*)d_in[0];
  const int*   ei = (const int*)d_in[1];     // [2, E] row-major, int32
  const float* W1 = (const float*)d_in[2];
  const float* b1 = (const float*)d_in[3];
  const float* W2 = (const float*)d_in[4];
  const float* b2 = (const float*)d_in[5];
  const float* Wf = (const float*)d_in[6];
  const float* bf = (const float*)d_in[7];
  float* out = (float*)d_out;

  const int* srcv = ei;
  const int* dstv = ei + N_EDGES;

  // workspace carve-up (256B aligned), ~41 MB total
  char* p = (char*)d_ws;
  auto take = [&](size_t bytes) { char* r = p; p += (bytes + 255) & ~(size_t)255; return r; };
  int*   deg     = (int*)take((size_t)N_NODES * 4);
  int*   rs      = (int*)take((size_t)(N_NODES + 1) * 4);
  int*   cursor  = (int*)take((size_t)N_NODES * 4);
  int*   csr     = (int*)take((size_t)N_EDGES * 4);
  float* dis     = (float*)take((size_t)N_NODES * 4);
  float* agg1    = (float*)take((size_t)N_NODES * 16);
  float* h1      = (float*)take((size_t)N_NODES * 64 * 4);
  int*   blksums = (int*)take(512 * 4);

  (void)hipMemsetAsync(deg, 0, (size_t)N_NODES * 4, stream);
  k_deg  <<<(N_EDGES + 255) / 256, 256, 0, stream>>>(dstv, deg);
  k_scan1<<<NB, 256, 0, stream>>>(deg, rs, dis, blksums);
  k_scan2<<<1, 512, 0, stream>>>(blksums);
  k_scan3<<<NB, 256, 0, stream>>>(rs, cursor, blksums);
  k_fill <<<(N_EDGES + 255) / 256, 256, 0, stream>>>(srcv, dstv, cursor, csr);
  k_agg1 <<<NB, 256, 0, stream>>>((const float4*)x, dis, rs, csr, (float4*)agg1);
  k_xform1<<<(N_NODES * 64 + 255) / 256, 256, 0, stream>>>((const float4*)agg1, W1, b1, h1);
  k_layer2<<<N_NODES / 4, 256, 0, stream>>>(h1, dis, rs, csr, W2, b2, Wf, bf, out);
}